// Round 3
// baseline (1111.274 us; speedup 1.0000x reference)
//
#include <hip/hip_runtime.h>
#include <cstdint>
#include <cstddef>

#define RANK_K 819            // kth = sorted[819] (820th smallest of 2048)
// conv: x[64,3,32,32] * w[2048,3,6,6] VALID -> [64,2048,27,27]

__device__ __forceinline__ int zbinf(float z) {
  // value-binned bucket over [-16,16), width 1/64. Monotone in z.
  float t = (z + 16.0f) * 64.0f;
  t = t < 0.0f ? 0.0f : (t > 2047.0f ? 2047.0f : t);
  return (int)t;
}

// ------- kernel 1: weight transpose w[c][ic][ky][kx] -> wt[(ky,kx,ic)][c] ---
// k-order = (ky*6+kx)*3+ic : ic innermost (XLA/Eigen NHWC-HWIO im2col order)
__global__ __launch_bounds__(256) void net99_wtrans(const float* __restrict__ w,
                                                    float* __restrict__ wt) {
  int idx = blockIdx.x * 256 + threadIdx.x;
  if (idx < 2048 * 108) {
    int kk = idx / 2048, c = idx % 2048;
    int ic = kk % 3, sp = kk / 3, ky = sp / 6, kx = sp % 6;
    wt[idx] = w[c * 108 + ic * 36 + ky * 6 + kx];   // coalesced write
  }
}

// ------- kernel 2: f32 conv, sequential-FMA in (ky,kx,ic) order -------------
// out layout [bl][y][x][c] (pixel-major, channel contiguous)
__global__ __launch_bounds__(256) void net99_conv(const float* __restrict__ x,
                                                  const float* __restrict__ wt,
                                                  float* __restrict__ conv, int b0) {
  const int y  = blockIdx.x;       // 0..26
  const int ct = blockIdx.y;       // 0..7 (channel tile of 256)
  const int bl = blockIdx.z;       // local batch
  const int b  = b0 + bl;
  const int tid = threadIdx.x;
  __shared__ float xs[3][6][34];   // cols 32,33 zero pad (OOB guard)
  for (int i = tid; i < 3 * 6 * 34; i += 256) {
    int ic = i / 204, rem = i % 204, r = rem / 34, col = rem % 34;
    xs[ic][r][col] = (col < 32) ? x[((b * 3 + ic) * 32 + (y + r)) * 32 + col] : 0.0f;
  }
  __syncthreads();
  const int c = ct * 256 + tid;
  for (int xh = 0; xh < 27; xh += 14) {
    float acc[14];
#pragma unroll
    for (int q = 0; q < 14; ++q) acc[q] = 0.0f;
    // strict sequential accumulation over k = (ky*6+kx)*3 + ic, ascending.
    // fmaf() = single-rounding FMA; chain order preserved (no fast-math).
    for (int ky = 0; ky < 6; ++ky) {
      for (int kx = 0; kx < 6; ++kx) {
#pragma unroll
        for (int ic = 0; ic < 3; ++ic) {
          float wv = wt[((ky * 6 + kx) * 3 + ic) * 2048 + c];
          const float* row = &xs[ic][ky][xh + kx];
#pragma unroll
          for (int q = 0; q < 14; ++q) acc[q] = fmaf(wv, row[q], acc[q]);
        }
      }
    }
    float* dst = conv + ((size_t)(bl * 27 + y) * 27) * 2048 + c;
#pragma unroll
    for (int q = 0; q < 14; ++q) {
      int xq = xh + q;
      if (xq < 27) dst[(size_t)xq * 2048] = acc[q];
    }
  }
}

// ------- kernel 3: per-pixel exact f32 rank-819 select + mask ---------------
// mask layout: msk[((s*64+gb)*729 + p)*64 + cw], bit (c&31) of word cw=c>>5
__global__ __launch_bounds__(256) void net99_select(const float* __restrict__ conv,
                                                    const float* __restrict__ bias,
                                                    uint32_t* __restrict__ msk, int b0) {
  const int bl = blockIdx.x / 729;
  const int p  = blockIdx.x % 729;
  const int gb = b0 + bl;
  const int tid = threadIdx.x;
  __shared__ float    vals[2048];
  __shared__ float    biasS[2048];
  __shared__ uint32_t hist[2][2048];
  __shared__ float    cand[512];
  __shared__ int      sbuf[256];
  __shared__ int      s_cnt, s_bin, s_below;
  __shared__ float    s_kth[2];

  const float* src = conv + ((size_t)bl * 729 + p) * 2048;
  for (int i = tid; i < 2048; i += 256) { vals[i] = src[i]; biasS[i] = bias[i]; }
  for (int i = tid; i < 4096; i += 256) (&hist[0][0])[i] = 0u;
  __syncthreads();
  for (int i = tid; i < 2048; i += 256) {
    float v = vals[i]; float bs = biasS[i];
    atomicAdd(&hist[0][zbinf(bs - v)], 1u);
    atomicAdd(&hist[1][zbinf(bs + v)], 1u);
  }
  __syncthreads();
  for (int s = 0; s < 2; ++s) {
    int loc = 0;
#pragma unroll
    for (int k = 0; k < 8; ++k) loc += (int)hist[s][tid * 8 + k];
    sbuf[tid] = loc; __syncthreads();
    for (int off = 1; off < 256; off <<= 1) {       // inclusive scan
      int v = sbuf[tid];
      int a = (tid >= off) ? sbuf[tid - off] : 0;
      __syncthreads();
      sbuf[tid] = v + a;
      __syncthreads();
    }
    int pre = sbuf[tid] - loc;
    if (tid == 0) s_cnt = 0;
    if (pre <= RANK_K && RANK_K < pre + loc) {      // exactly one thread
      int cum = pre;
      for (int k = 0; k < 8; ++k) {
        int h = (int)hist[s][tid * 8 + k];
        if (RANK_K < cum + h) { s_bin = tid * 8 + k; s_below = cum; break; }
        cum += h;
      }
    }
    __syncthreads();
    int tb = s_bin, below = s_below;
    for (int i = tid; i < 2048; i += 256) {         // compact target bin
      float v = vals[i]; float bs = biasS[i];
      float z = s ? (bs + v) : (bs - v);
      if (zbinf(z) == tb) { int pos = atomicAdd(&s_cnt, 1); if (pos < 512) cand[pos] = z; }
    }
    __syncthreads();
    int cnt = s_cnt; if (cnt > 512) cnt = 512;
    int rloc = RANK_K - below;
    for (int ci = tid; ci < cnt; ci += 256) {       // exact rank among candidates
      float v = cand[ci]; int rk = 0;
      for (int j = 0; j < cnt; ++j) {
        float u = cand[j];
        rk += (u < v) || (u == v && j < ci);
      }
      if (rk == rloc) s_kth[s] = v;
    }
    __syncthreads();
  }
  float km = s_kth[0], kp = s_kth[1];
  size_t base0 = ((size_t)(0 * 64 + gb) * 729 + p) * 64;
  size_t base1 = ((size_t)(1 * 64 + gb) * 729 + p) * 64;
  int lane = tid & 63;
  for (int i = 0; i < 8; ++i) {
    int idx = i * 256 + tid;
    float v = vals[idx]; float bs = biasS[idx];
    unsigned long long bm = __ballot((bs - v) < km);
    unsigned long long bp = __ballot((bs + v) < kp);
    if (lane == 0 || lane == 32) {
      uint32_t m0 = (lane == 0) ? (uint32_t)bm : (uint32_t)(bm >> 32);
      uint32_t m1 = (lane == 0) ? (uint32_t)bp : (uint32_t)(bp >> 32);
      int wv = idx >> 5;
      msk[base0 + wv] = m0;
      msk[base1 + wv] = m1;
    }
  }
}

// ------- kernel 4: bit-exact avg_pool(5,3,ceil) + adaptive(6) ---------------
__global__ __launch_bounds__(256) void net99_pool(const uint32_t* __restrict__ msk,
                                                  float* __restrict__ out) {
  int idx = blockIdx.x * 256 + threadIdx.x;        // 0..262143 = (s,b,c)
  int s = idx >> 17;
  int b = (idx >> 11) & 63;
  int c = idx & 2047;
  const uint32_t* mrow = msk + ((size_t)(s * 64 + b) * 729) * 64 + (c >> 5);
  uint32_t sel = c & 31;
  uint32_t rbm[27];
  for (int y = 0; y < 27; ++y) {
    uint32_t rb = 0;
#pragma unroll
    for (int xx = 0; xx < 27; ++xx)
      rb |= ((mrow[(size_t)(y * 27 + xx) * 64] >> sel) & 1u) << xx;
    rbm[y] = rb;
  }
  constexpr uint32_t WM[9] = {0x1Fu, 0xF8u, 0x7C0u, 0x3E00u, 0x1F000u,
                              0xF8000u, 0x7C0000u, 0x3E00000u, 0x7000000u};
  constexpr int CC[9]   = {5, 5, 5, 5, 5, 5, 5, 5, 3};
  constexpr int BW0[6]  = {0, 1, 3, 4, 6, 7};
  constexpr int BW1[6]  = {1, 2, 4, 5, 7, 8};
  float* dst = out + (size_t)s * 4718592 + (size_t)(b * 2048 + c) * 36;
  for (int i = 0; i < 6; ++i) {
    float P[2][9];
#pragma unroll
    for (int t = 0; t < 2; ++t) {
      int r  = t ? BW1[i] : BW0[i];
      int y0 = 3 * r;
      int y1 = (y0 + 5 > 27) ? 27 : y0 + 5;
      int cr = y1 - y0;
      int pp[9];
#pragma unroll
      for (int cx = 0; cx < 9; ++cx) pp[cx] = 0;
      for (int y = y0; y < y1; ++y) {
        uint32_t rb = rbm[y];
#pragma unroll
        for (int cx = 0; cx < 9; ++cx) pp[cx] += __popc(rb & WM[cx]);
      }
#pragma unroll
      for (int cx = 0; cx < 9; ++cx)
        P[t][cx] = (float)pp[cx] / (float)(cr * CC[cx]);   // IEEE f32 div
    }
    float M[9];
#pragma unroll
    for (int cx = 0; cx < 9; ++cx) M[cx] = (P[0][cx] + P[1][cx]) * 0.5f;
#pragma unroll
    for (int j = 0; j < 6; ++j)
      dst[i * 6 + j] = (M[BW0[j]] + M[BW1[j]]) * 0.5f;
  }
}

extern "C" void kernel_launch(void* const* d_in, const int* in_sizes, int n_in,
                              void* d_out, int out_size, void* d_ws, size_t ws_size,
                              hipStream_t stream) {
  const float* x    = (const float*)d_in[0];
  const float* w    = (const float*)d_in[1];
  const float* bias = (const float*)d_in[2];
  float* out = (float*)d_out;
  uint8_t* ws = (uint8_t*)d_ws;

  const size_t WT_BYTES   = (size_t)108 * 2048 * 4;          //   884,736
  const size_t MASK_OFF   = WT_BYTES;
  const size_t MASK_BYTES = (size_t)2 * 64 * 729 * 64 * 4;   // 23,887,872
  const size_t CONV_OFF   = MASK_OFF + MASK_BYTES;           // 24,772,608
  const size_t PER_B      = (size_t)2048 * 729 * 4;          // 5,971,968 per batch

  float*    wt   = (float*)ws;
  uint32_t* msk  = (uint32_t*)(ws + MASK_OFF);
  float*    conv = (float*)(ws + CONV_OFF);

  size_t avail = ws_size > CONV_OFF ? ws_size - CONV_OFF : 0;
  int Bc = (int)(avail / PER_B);
  if (Bc < 1) Bc = 1;       // assumes ws_size >= ~31 MB
  if (Bc > 64) Bc = 64;

  hipLaunchKernelGGL(net99_wtrans, dim3((2048 * 108 + 255) / 256), dim3(256), 0, stream, w, wt);
  for (int b0 = 0; b0 < 64; b0 += Bc) {
    int nb = (64 - b0 < Bc) ? (64 - b0) : Bc;
    hipLaunchKernelGGL(net99_conv, dim3(27, 8, nb), dim3(256), 0, stream, x, wt, conv, b0);
    hipLaunchKernelGGL(net99_select, dim3(nb * 729), dim3(256), 0, stream, conv, bias, msk, b0);
  }
  hipLaunchKernelGGL(net99_pool, dim3(1024), dim3(256), 0, stream, msk, out);
}

// Round 4
// 590.539 us; speedup vs baseline: 1.8818x; 1.8818x over previous
//
#include <hip/hip_runtime.h>
#include <cstdint>
#include <cstddef>

#define RANK_K 819            // kth = sorted[819] (820th smallest of 2048)
// conv: x[64,3,32,32] * w[2048,3,6,6] VALID -> [64,2048,27,27]

__device__ __forceinline__ int zbin256(float z) {
  // 256 bins over [-8,8), width 1/16. Monotone partition; selection is exact
  // rank within bin, so binning never affects the kth VALUE.
  float t = (z + 8.0f) * 16.0f;
  t = t < 0.0f ? 0.0f : (t > 255.0f ? 255.0f : t);
  return (int)t;
}

// ------- kernel 1: weight transpose w[c][ic][ky][kx] -> wt[(ky,kx,ic)][c] ---
__global__ __launch_bounds__(256) void net99_wtrans(const float* __restrict__ w,
                                                    float* __restrict__ wt) {
  int idx = blockIdx.x * 256 + threadIdx.x;
  if (idx < 2048 * 108) {
    int kk = idx / 2048, c = idx % 2048;
    int ic = kk % 3, sp = kk / 3, ky = sp / 6, kx = sp % 6;
    wt[idx] = w[c * 108 + ic * 36 + ky * 6 + kx];   // coalesced write
  }
}

// ------- kernel 2: f32 conv, sequential-FMA in (ky,kx,ic) order -------------
// Register-resident x rows; identical fmaf chain order as the passing kernel.
__global__ __launch_bounds__(256) void net99_conv(const float* __restrict__ x,
                                                  const float* __restrict__ wt,
                                                  float* __restrict__ conv, int b0) {
  const int y  = blockIdx.x;       // 0..26
  const int ct = blockIdx.y;       // 0..7 (channel tile of 256)
  const int bl = blockIdx.z;       // local batch
  const int b  = b0 + bl;
  const int tid = threadIdx.x;
  __shared__ float xs[3][6][32];
  for (int i = tid; i < 576; i += 256) {
    int ic = i / 192, rem = i % 192, r = rem / 32, col = rem % 32;
    xs[ic][r][col] = x[((b * 3 + ic) * 32 + (y + r)) * 32 + col];
  }
  __syncthreads();
  const int c = ct * 256 + tid;
  const float* wtc = wt + c;
  float acc[27];
#pragma unroll
  for (int q = 0; q < 27; ++q) acc[q] = 0.0f;
  for (int ky = 0; ky < 6; ++ky) {   // NOT unrolled: bounds register pressure
    float xd[3][32];
#pragma unroll
    for (int i = 0; i < 96; ++i) {   // contiguous -> ds_read_b128 bursts
      int ic = i >> 5, col = i & 31;
      xd[ic][col] = xs[ic][ky][col];
    }
#pragma unroll
    for (int kx = 0; kx < 6; ++kx) {
#pragma unroll
      for (int ic = 0; ic < 3; ++ic) {
        float wv = wtc[(size_t)((ky * 6 + kx) * 3 + ic) * 2048];
#pragma unroll
        for (int q = 0; q < 27; ++q)
          acc[q] = fmaf(wv, xd[ic][kx + q], acc[q]);   // strict chain order
      }
    }
  }
  float* dst = conv + ((size_t)(bl * 27 + y) * 27) * 2048 + c;
#pragma unroll
  for (int q = 0; q < 27; ++q) dst[(size_t)q * 2048] = acc[q];
}

// ------- kernel 3: per-pixel exact f32 rank-819 select + mask ---------------
// mask layout: msk[((s*64+gb)*729 + p)*64 + cw], bit (c&31) of word cw=c>>5
__global__ __launch_bounds__(256) void net99_select(const float* __restrict__ conv,
                                                    const float* __restrict__ bias,
                                                    uint32_t* __restrict__ msk, int b0) {
  const int bl = blockIdx.x / 729;
  const int p  = blockIdx.x % 729;
  const int gb = b0 + bl;
  const int tid = threadIdx.x;
  __shared__ __align__(16) float vals[2048];
  __shared__ __align__(16) float biasS[2048];
  __shared__ uint32_t hist[2][256];
  __shared__ float    cand[2][512];
  __shared__ int      cnt[2];
  __shared__ int      wsum[2][4];
  __shared__ int      sbin[2], sbelow[2];
  __shared__ float    skth[2];

  const float4* src4 = (const float4*)(conv + ((size_t)bl * 729 + p) * 2048);
  const float4* b4   = (const float4*)bias;
  ((float4*)vals)[tid]        = src4[tid];
  ((float4*)vals)[tid + 256]  = src4[tid + 256];
  ((float4*)biasS)[tid]       = b4[tid];
  ((float4*)biasS)[tid + 256] = b4[tid + 256];
  (&hist[0][0])[tid]       = 0u;
  (&hist[0][0])[tid + 256] = 0u;
  if (tid < 2) cnt[tid] = 0;
  __syncthreads();
  for (int i = tid; i < 2048; i += 256) {
    float v = vals[i], bs = biasS[i];
    atomicAdd(&hist[0][zbin256(bs - v)], 1u);
    atomicAdd(&hist[1][zbin256(bs + v)], 1u);
  }
  __syncthreads();
  // dual inclusive scan over 256 bins (wave shfl + 4 wave partials)
  int h0 = (int)hist[0][tid], h1 = (int)hist[1][tid];
  int v0 = h0, v1 = h1;
  int lane = tid & 63, wid = tid >> 6;
#pragma unroll
  for (int off = 1; off < 64; off <<= 1) {
    int u0 = __shfl_up(v0, off), u1 = __shfl_up(v1, off);
    if (lane >= off) { v0 += u0; v1 += u1; }
  }
  if (lane == 63) { wsum[0][wid] = v0; wsum[1][wid] = v1; }
  __syncthreads();
  if (tid < 2) {
    int a = 0;
#pragma unroll
    for (int w = 0; w < 4; ++w) { int t = wsum[tid][w]; wsum[tid][w] = a; a += t; }
  }
  __syncthreads();
  int pre0 = v0 - h0 + wsum[0][wid];
  int pre1 = v1 - h1 + wsum[1][wid];
  if (pre0 <= RANK_K && RANK_K < pre0 + h0) { sbin[0] = tid; sbelow[0] = pre0; }
  if (pre1 <= RANK_K && RANK_K < pre1 + h1) { sbin[1] = tid; sbelow[1] = pre1; }
  __syncthreads();
  int tb0 = sbin[0], tb1 = sbin[1];
  for (int i = tid; i < 2048; i += 256) {          // compact both target bins
    float v = vals[i], bs = biasS[i];
    float z0 = bs - v, z1 = bs + v;
    if (zbin256(z0) == tb0) { int q = atomicAdd(&cnt[0], 1); if (q < 512) cand[0][q] = z0; }
    if (zbin256(z1) == tb1) { int q = atomicAdd(&cnt[1], 1); if (q < 512) cand[1][q] = z1; }
  }
  __syncthreads();
#pragma unroll
  for (int s = 0; s < 2; ++s) {                    // exact rank among candidates
    int cN = cnt[s] < 512 ? cnt[s] : 512;
    int rloc = RANK_K - sbelow[s];
    for (int ci = tid; ci < cN; ci += 256) {
      float v = cand[s][ci]; int rk = 0;
      for (int j = 0; j < cN; ++j) {
        float u = cand[s][j];
        rk += (u < v) || (u == v && j < ci);
      }
      if (rk == rloc) skth[s] = v;
    }
  }
  __syncthreads();
  float km = skth[0], kp = skth[1];
  size_t base0 = ((size_t)(0 * 64 + gb) * 729 + p) * 64;
  size_t base1 = ((size_t)(1 * 64 + gb) * 729 + p) * 64;
  for (int i = 0; i < 8; ++i) {
    int idx = i * 256 + tid;
    float v = vals[idx], bs = biasS[idx];
    unsigned long long bm = __ballot((bs - v) < km);
    unsigned long long bp = __ballot((bs + v) < kp);
    if (lane == 0 || lane == 32) {
      uint32_t m0 = (lane == 0) ? (uint32_t)bm : (uint32_t)(bm >> 32);
      uint32_t m1 = (lane == 0) ? (uint32_t)bp : (uint32_t)(bp >> 32);
      int wv = idx >> 5;
      msk[base0 + wv] = m0;
      msk[base1 + wv] = m1;
    }
  }
}

// ------- kernel 4: bit-exact avg_pool(5,3,ceil) + adaptive(6), LDS-staged ---
__global__ __launch_bounds__(256) void net99_pool(const uint32_t* __restrict__ msk,
                                                  float* __restrict__ out) {
  __shared__ uint32_t stage[729 * 8];   // 23,328 B: full (s,b,cg) mask slice
  const int blk = blockIdx.x;           // 0..1023 = (sb, cg)
  const int cg  = blk & 7;
  const int sb  = blk >> 3;             // s*64 + b
  const int tid = threadIdx.x;
  const uint32_t* src = msk + (size_t)sb * 729 * 64 + cg * 8;
  for (int i = tid; i < 729 * 8; i += 256) {
    int p = i >> 3, w = i & 7;
    stage[i] = src[(size_t)p * 64 + w];
  }
  __syncthreads();
  const int lw = tid >> 5, sel = tid & 31;
  uint32_t rbm[27];
  for (int y = 0; y < 27; ++y) {
    uint32_t rb = 0;
#pragma unroll
    for (int xx = 0; xx < 27; ++xx)
      rb |= ((stage[(y * 27 + xx) * 8 + lw] >> sel) & 1u) << xx;
    rbm[y] = rb;
  }
  constexpr uint32_t WM[9] = {0x1Fu, 0xF8u, 0x7C0u, 0x3E00u, 0x1F000u,
                              0xF8000u, 0x7C0000u, 0x3E00000u, 0x7000000u};
  constexpr int CC[9]  = {5, 5, 5, 5, 5, 5, 5, 5, 3};
  constexpr int BW0[6] = {0, 1, 3, 4, 6, 7};
  constexpr int BW1[6] = {1, 2, 4, 5, 7, 8};
  const int s = sb >> 6, b = sb & 63, c = cg * 256 + tid;
  float* dst = out + (size_t)s * 4718592 + (size_t)(b * 2048 + c) * 36;
  for (int i = 0; i < 6; ++i) {
    float P[2][9];
#pragma unroll
    for (int t = 0; t < 2; ++t) {
      int r  = t ? BW1[i] : BW0[i];
      int y0 = 3 * r;
      int y1 = (y0 + 5 > 27) ? 27 : y0 + 5;
      int cr = y1 - y0;
      int pp[9];
#pragma unroll
      for (int cx = 0; cx < 9; ++cx) pp[cx] = 0;
      for (int yy = y0; yy < y1; ++yy) {
        uint32_t rb = rbm[yy];
#pragma unroll
        for (int cx = 0; cx < 9; ++cx) pp[cx] += __popc(rb & WM[cx]);
      }
#pragma unroll
      for (int cx = 0; cx < 9; ++cx)
        P[t][cx] = (float)pp[cx] / (float)(cr * CC[cx]);   // IEEE f32 div
    }
    float M[9];
#pragma unroll
    for (int cx = 0; cx < 9; ++cx) M[cx] = (P[0][cx] + P[1][cx]) * 0.5f;
#pragma unroll
    for (int j = 0; j < 6; ++j)
      dst[i * 6 + j] = (M[BW0[j]] + M[BW1[j]]) * 0.5f;
  }
}

extern "C" void kernel_launch(void* const* d_in, const int* in_sizes, int n_in,
                              void* d_out, int out_size, void* d_ws, size_t ws_size,
                              hipStream_t stream) {
  const float* x    = (const float*)d_in[0];
  const float* w    = (const float*)d_in[1];
  const float* bias = (const float*)d_in[2];
  float* out = (float*)d_out;
  uint8_t* ws = (uint8_t*)d_ws;

  const size_t WT_BYTES   = (size_t)108 * 2048 * 4;          //   884,736
  const size_t MASK_OFF   = WT_BYTES;
  const size_t MASK_BYTES = (size_t)2 * 64 * 729 * 64 * 4;   // 23,887,872
  const size_t CONV_OFF   = MASK_OFF + MASK_BYTES;           // 24,772,608
  const size_t PER_B      = (size_t)2048 * 729 * 4;          // 5,971,968 per batch

  float*    wt   = (float*)ws;
  uint32_t* msk  = (uint32_t*)(ws + MASK_OFF);
  float*    conv = (float*)(ws + CONV_OFF);

  size_t avail = ws_size > CONV_OFF ? ws_size - CONV_OFF : 0;
  int Bc = (int)(avail / PER_B);
  if (Bc < 1) Bc = 1;       // assumes ws_size >= ~31 MB
  if (Bc > 64) Bc = 64;

  hipLaunchKernelGGL(net99_wtrans, dim3((2048 * 108 + 255) / 256), dim3(256), 0, stream, w, wt);
  for (int b0 = 0; b0 < 64; b0 += Bc) {
    int nb = (64 - b0 < Bc) ? (64 - b0) : Bc;
    hipLaunchKernelGGL(net99_conv, dim3(27, 8, nb), dim3(256), 0, stream, x, wt, conv, b0);
    hipLaunchKernelGGL(net99_select, dim3(nb * 729), dim3(256), 0, stream, conv, bias, msk, b0);
  }
  hipLaunchKernelGGL(net99_pool, dim3(1024), dim3(256), 0, stream, msk, out);
}

// Round 5
// 503.898 us; speedup vs baseline: 2.2054x; 1.1719x over previous
//
#include <hip/hip_runtime.h>
#include <cstdint>
#include <cstddef>

#define RANK_K 819            // kth = sorted[819] (820th smallest of 2048)
// conv: x[64,3,32,32] * w[2048,3,6,6] VALID -> [64,2048,27,27]

__device__ __forceinline__ int zbin256(float z) {
  // 256 bins over [-8,8), width 1/16. Monotone partition; selection is exact
  // rank within bin, so binning never affects the kth VALUE.
  float t = (z + 8.0f) * 16.0f;
  t = t < 0.0f ? 0.0f : (t > 255.0f ? 255.0f : t);
  return (int)t;
}

// ------- kernel 1: weight transpose w[c][ic][ky][kx] -> wt[(ky,kx,ic)][c] ---
__global__ __launch_bounds__(256) void net99_wtrans(const float* __restrict__ w,
                                                    float* __restrict__ wt) {
  int idx = blockIdx.x * 256 + threadIdx.x;
  if (idx < 2048 * 108) {
    int kk = idx / 2048, c = idx % 2048;
    int ic = kk % 3, sp = kk / 3, ky = sp / 6, kx = sp % 6;
    wt[idx] = w[c * 108 + ic * 36 + ky * 6 + kx];   // coalesced write
  }
}

// ------- kernel 2: f32 conv, sequential-FMA in (ky,kx,ic) order -------------
// UNCHANGED from the passing round (bit-exact chain order). Do not touch.
__global__ __launch_bounds__(256) void net99_conv(const float* __restrict__ x,
                                                  const float* __restrict__ wt,
                                                  float* __restrict__ conv, int b0) {
  const int y  = blockIdx.x;       // 0..26
  const int ct = blockIdx.y;       // 0..7 (channel tile of 256)
  const int bl = blockIdx.z;       // local batch
  const int b  = b0 + bl;
  const int tid = threadIdx.x;
  __shared__ float xs[3][6][32];
  for (int i = tid; i < 576; i += 256) {
    int ic = i / 192, rem = i % 192, r = rem / 32, col = rem % 32;
    xs[ic][r][col] = x[((b * 3 + ic) * 32 + (y + r)) * 32 + col];
  }
  __syncthreads();
  const int c = ct * 256 + tid;
  const float* wtc = wt + c;
  float acc[27];
#pragma unroll
  for (int q = 0; q < 27; ++q) acc[q] = 0.0f;
  for (int ky = 0; ky < 6; ++ky) {   // NOT unrolled: bounds register pressure
    float xd[3][32];
#pragma unroll
    for (int i = 0; i < 96; ++i) {   // contiguous -> ds_read_b128 bursts
      int ic = i >> 5, col = i & 31;
      xd[ic][col] = xs[ic][ky][col];
    }
#pragma unroll
    for (int kx = 0; kx < 6; ++kx) {
#pragma unroll
      for (int ic = 0; ic < 3; ++ic) {
        float wv = wtc[(size_t)((ky * 6 + kx) * 3 + ic) * 2048];
#pragma unroll
        for (int q = 0; q < 27; ++q)
          acc[q] = fmaf(wv, xd[ic][kx + q], acc[q]);   // strict chain order
      }
    }
  }
  float* dst = conv + ((size_t)(bl * 27 + y) * 27) * 2048 + c;
#pragma unroll
  for (int q = 0; q < 27; ++q) dst[(size_t)q * 2048] = acc[q];
}

// ------- kernel 3: register-resident f32 rank-819 select + byte mask --------
// Thread t owns channels c = t*8..t*8+7 (two float4 loads). z-values stay in
// VGPRs end-to-end. 4 barriers. Mask written as bytes: byte index within the
// 256-byte pixel mask = c/8 = t (little-endian uint32 word layout).
__global__ __launch_bounds__(256) void net99_select(const float* __restrict__ conv,
                                                    const float* __restrict__ bias,
                                                    uint8_t* __restrict__ mskb, int b0) {
  const int bl = blockIdx.x / 729;
  const int p  = blockIdx.x % 729;
  const int gb = b0 + bl;
  const int tid  = threadIdx.x;
  const int lane = tid & 63;
  const int wid  = tid >> 6;
  __shared__ uint32_t hist[2][256];
  __shared__ float    cand[2][512];
  __shared__ int      cnt[2];
  __shared__ int      sbin[2], sbelow[2];
  __shared__ float    skth[2];

  // issue global loads first (hide latency under init)
  const float4* __restrict__ src4 =
      (const float4*)(conv + ((size_t)bl * 729 + p) * 2048) + tid * 2;
  const float4* __restrict__ b4 = (const float4*)bias + tid * 2;
  float4 va = src4[0], vb = src4[1];
  float4 ba = b4[0],   bb = b4[1];

  hist[0][tid] = 0u; hist[1][tid] = 0u;
  if (tid < 2) cnt[tid] = 0;

  float z0[8], z1[8];
  z0[0] = ba.x - va.x; z1[0] = ba.x + va.x;
  z0[1] = ba.y - va.y; z1[1] = ba.y + va.y;
  z0[2] = ba.z - va.z; z1[2] = ba.z + va.z;
  z0[3] = ba.w - va.w; z1[3] = ba.w + va.w;
  z0[4] = bb.x - vb.x; z1[4] = bb.x + vb.x;
  z0[5] = bb.y - vb.y; z1[5] = bb.y + vb.y;
  z0[6] = bb.z - vb.z; z1[6] = bb.z + vb.z;
  z0[7] = bb.w - vb.w; z1[7] = bb.w + vb.w;
  __syncthreads();                                  // hist zeros visible
#pragma unroll
  for (int j = 0; j < 8; ++j) {
    atomicAdd(&hist[0][zbin256(z0[j])], 1u);
    atomicAdd(&hist[1][zbin256(z1[j])], 1u);
  }
  __syncthreads();
  // scan phase: wave0 -> branch0, wave1 -> branch1 (wave-synchronous, no barriers)
  if (wid < 2) {
    const int s = wid;
    int h[4];
#pragma unroll
    for (int t = 0; t < 4; ++t) h[t] = (int)hist[s][lane * 4 + t];
    int loc = h[0] + h[1] + h[2] + h[3];
    int inc = loc;
#pragma unroll
    for (int off = 1; off < 64; off <<= 1) {
      int u = __shfl_up(inc, off);
      if (lane >= off) inc += u;
    }
    int pre = inc - loc;                            // values below this lane's 4 bins
    if (pre <= RANK_K && RANK_K < pre + loc) {      // exactly one lane
      int cum = pre;
#pragma unroll
      for (int t = 0; t < 4; ++t) {
        if (RANK_K < cum + h[t]) { sbin[s] = lane * 4 + t; sbelow[s] = cum; break; }
        cum += h[t];
      }
    }
  }
  __syncthreads();
  const int tb0 = sbin[0], tb1 = sbin[1];
#pragma unroll
  for (int j = 0; j < 8; ++j) {                     // compact from registers
    if (zbin256(z0[j]) == tb0) { int q = atomicAdd(&cnt[0], 1); if (q < 512) cand[0][q] = z0[j]; }
    if (zbin256(z1[j]) == tb1) { int q = atomicAdd(&cnt[1], 1); if (q < 512) cand[1][q] = z1[j]; }
  }
  __syncthreads();
  if (wid < 2) {                                    // exact rank, one wave per branch
    const int s = wid;
    int cN = cnt[s] < 512 ? cnt[s] : 512;
    int rloc = RANK_K - sbelow[s];
    for (int ci = lane; ci < cN; ci += 64) {
      float v = cand[s][ci]; int rk = 0;
      for (int j = 0; j < cN; ++j) {
        float u = cand[s][j];
        rk += (u < v) || (u == v && j < ci);
      }
      if (rk == rloc) skth[s] = v;                  // unique winning VALUE
    }
  }
  __syncthreads();
  const float km = skth[0], kp = skth[1];
  uint32_t m0 = 0u, m1 = 0u;
#pragma unroll
  for (int j = 0; j < 8; ++j) {
    m0 |= (uint32_t)(z0[j] < km) << j;
    m1 |= (uint32_t)(z1[j] < kp) << j;
  }
  const size_t pix = (size_t)gb * 729 + p;
  mskb[(pix)*256 + tid]                      = (uint8_t)m0;   // branch 0
  mskb[((size_t)64 * 729 + pix) * 256 + tid] = (uint8_t)m1;   // branch 1
}

// ------- kernel 4: bit-exact avg_pool(5,3,ceil) + adaptive(6), LDS-staged ---
__global__ __launch_bounds__(256) void net99_pool(const uint32_t* __restrict__ msk,
                                                  float* __restrict__ out) {
  __shared__ uint32_t stage[729 * 8];   // 23,328 B: full (s,b,cg) mask slice
  const int blk = blockIdx.x;           // 0..1023 = (sb, cg)
  const int cg  = blk & 7;
  const int sb  = blk >> 3;             // s*64 + b
  const int tid = threadIdx.x;
  const uint32_t* src = msk + (size_t)sb * 729 * 64 + cg * 8;
  for (int i = tid; i < 729 * 8; i += 256) {
    int p = i >> 3, w = i & 7;
    stage[i] = src[(size_t)p * 64 + w];
  }
  __syncthreads();
  const int lw = tid >> 5, sel = tid & 31;
  uint32_t rbm[27];
  for (int y = 0; y < 27; ++y) {
    uint32_t rb = 0;
#pragma unroll
    for (int xx = 0; xx < 27; ++xx)
      rb |= ((stage[(y * 27 + xx) * 8 + lw] >> sel) & 1u) << xx;
    rbm[y] = rb;
  }
  constexpr uint32_t WM[9] = {0x1Fu, 0xF8u, 0x7C0u, 0x3E00u, 0x1F000u,
                              0xF8000u, 0x7C0000u, 0x3E00000u, 0x7000000u};
  constexpr int CC[9]  = {5, 5, 5, 5, 5, 5, 5, 5, 3};
  constexpr int BW0[6] = {0, 1, 3, 4, 6, 7};
  constexpr int BW1[6] = {1, 2, 4, 5, 7, 8};
  const int s = sb >> 6, b = sb & 63, c = cg * 256 + tid;
  float* dst = out + (size_t)s * 4718592 + (size_t)(b * 2048 + c) * 36;
  for (int i = 0; i < 6; ++i) {
    float P[2][9];
#pragma unroll
    for (int t = 0; t < 2; ++t) {
      int r  = t ? BW1[i] : BW0[i];
      int y0 = 3 * r;
      int y1 = (y0 + 5 > 27) ? 27 : y0 + 5;
      int cr = y1 - y0;
      int pp[9];
#pragma unroll
      for (int cx = 0; cx < 9; ++cx) pp[cx] = 0;
      for (int yy = y0; yy < y1; ++yy) {
        uint32_t rb = rbm[yy];
#pragma unroll
        for (int cx = 0; cx < 9; ++cx) pp[cx] += __popc(rb & WM[cx]);
      }
#pragma unroll
      for (int cx = 0; cx < 9; ++cx)
        P[t][cx] = (float)pp[cx] / (float)(cr * CC[cx]);   // IEEE f32 div
    }
    float M[9];
#pragma unroll
    for (int cx = 0; cx < 9; ++cx) M[cx] = (P[0][cx] + P[1][cx]) * 0.5f;
#pragma unroll
    for (int j = 0; j < 6; ++j)
      dst[i * 6 + j] = (M[BW0[j]] + M[BW1[j]]) * 0.5f;
  }
}

extern "C" void kernel_launch(void* const* d_in, const int* in_sizes, int n_in,
                              void* d_out, int out_size, void* d_ws, size_t ws_size,
                              hipStream_t stream) {
  const float* x    = (const float*)d_in[0];
  const float* w    = (const float*)d_in[1];
  const float* bias = (const float*)d_in[2];
  float* out = (float*)d_out;
  uint8_t* ws = (uint8_t*)d_ws;

  const size_t WT_BYTES   = (size_t)108 * 2048 * 4;          //   884,736
  const size_t MASK_OFF   = WT_BYTES;
  const size_t MASK_BYTES = (size_t)2 * 64 * 729 * 64 * 4;   // 23,887,872
  const size_t CONV_OFF   = MASK_OFF + MASK_BYTES;           // 24,772,608
  const size_t PER_B      = (size_t)2048 * 729 * 4;          // 5,971,968 per batch

  float*    wt   = (float*)ws;
  uint8_t*  mskb = (uint8_t*)(ws + MASK_OFF);
  uint32_t* msk  = (uint32_t*)(ws + MASK_OFF);
  float*    conv = (float*)(ws + CONV_OFF);

  size_t avail = ws_size > CONV_OFF ? ws_size - CONV_OFF : 0;
  int Bc = (int)(avail / PER_B);
  if (Bc < 1) Bc = 1;       // assumes ws_size >= ~31 MB
  if (Bc > 64) Bc = 64;

  hipLaunchKernelGGL(net99_wtrans, dim3((2048 * 108 + 255) / 256), dim3(256), 0, stream, w, wt);
  for (int b0 = 0; b0 < 64; b0 += Bc) {
    int nb = (64 - b0 < Bc) ? (64 - b0) : Bc;
    hipLaunchKernelGGL(net99_conv, dim3(27, 8, nb), dim3(256), 0, stream, x, wt, conv, b0);
    hipLaunchKernelGGL(net99_select, dim3(nb * 729), dim3(256), 0, stream, conv, bias, mskb, b0);
  }
  hipLaunchKernelGGL(net99_pool, dim3(1024), dim3(256), 0, stream, msk, out);
}